// Round 1
// baseline (2076.782 us; speedup 1.0000x reference)
//
#include <hip/hip_runtime.h>

#define DEVINL __device__ __forceinline__

typedef unsigned short u16;
typedef __attribute__((ext_vector_type(8))) short short8;
typedef __attribute__((ext_vector_type(8))) unsigned short ushort8v;
typedef __attribute__((ext_vector_type(4))) float f32x4;

typedef const __attribute__((address_space(1))) void* gas1_t;
typedef __attribute__((address_space(3))) void* las3_t;

DEVINL u16 bf16_rn(float v) {
    union { float f; unsigned u; } x; x.f = v;
    unsigned r = x.u + 0x7FFFu + ((x.u >> 16) & 1u);
    return (u16)(r >> 16);
}
DEVINL float bf16_f(u16 h) {
    union { unsigned u; float f; } x; x.u = ((unsigned)h) << 16; return x.f;
}

DEVINL void load_lds16(const void* g, void* l) {
    __builtin_amdgcn_global_load_lds((gas1_t)g, (las3_t)l, 16, 0, 0);
}

// ---------------------------------------------------------------------------
// pack x: fp32 [rows][K] -> bf16 [rows][2K] as (hi | lo)
// ---------------------------------------------------------------------------
__global__ void pack_x_kernel(const float* __restrict__ X, u16* __restrict__ out,
                              int K, long total4) {
    long i = (long)blockIdx.x * blockDim.x + threadIdx.x;
    if (i >= total4) return;
    int kq = K >> 2;
    long s = i / kq;
    int c4 = (int)(i % kq);
    float4 v = ((const float4*)X)[i];
    u16 h0 = bf16_rn(v.x), h1 = bf16_rn(v.y), h2 = bf16_rn(v.z), h3 = bf16_rn(v.w);
    u16 l0 = bf16_rn(v.x - bf16_f(h0));
    u16 l1 = bf16_rn(v.y - bf16_f(h1));
    u16 l2 = bf16_rn(v.z - bf16_f(h2));
    u16 l3 = bf16_rn(v.w - bf16_f(h3));
    *(ushort4*)(out + s * (2L * K) + 4L * c4)     = make_ushort4(h0, h1, h2, h3);
    *(ushort4*)(out + s * (2L * K) + K + 4L * c4) = make_ushort4(l0, l1, l2, l3);
}

// ---------------------------------------------------------------------------
// pack + transpose W: fp32 [K][N] -> bf16 [N][2K] as (hi | lo)
// ---------------------------------------------------------------------------
__global__ void pack_transpose(const float* __restrict__ W, u16* __restrict__ out,
                               int K, int N) {
    __shared__ float tile[32][33];
    int nb = blockIdx.x * 32, kb = blockIdx.y * 32;
    int tx = threadIdx.x, ty = threadIdx.y;
#pragma unroll
    for (int i = ty; i < 32; i += 8)
        tile[i][tx] = W[(size_t)(kb + i) * N + nb + tx];
    __syncthreads();
#pragma unroll
    for (int i = ty; i < 32; i += 8) {
        int n = nb + i, k = kb + tx;
        float v = tile[tx][i];
        u16 h = bf16_rn(v);
        u16 l = bf16_rn(v - bf16_f(h));
        out[(size_t)n * (2 * K) + k]     = h;
        out[(size_t)n * (2 * K) + K + k] = l;
    }
}

// ---------------------------------------------------------------------------
// GEMM: C[M][N] = A'[M][K'=12288] * B'[N][K']^T (+bias), bf16x3 compensated.
// Physical storage of A2/B2 is [rows][8192] = (hi | lo); logical K' sections:
//   A: [ah | al | ah]  -> kA = k0>=8192 ? k0-8192 : k0
//   B: [bh | bh | bl]  -> kB = k0>=4096 ? k0-4096 : k0
// MODE 0: fp32 out + bias. MODE 1: bf16 out, relu(v+bias).
// 128x128 tile, BK=64, 4 waves (2x2 of 64x64), mfma_f32_16x16x32_bf16.
// LDS tiles XOR-swizzled: 16B slot c of row r holds k-group (c ^ (r&7)).
// ---------------------------------------------------------------------------
DEVINL void stage_tile(const u16* __restrict__ gsrc, u16* ldsdst, int wave, int lane) {
#pragma unroll
    for (int j = 0; j < 4; ++j) {
        int R = wave * 4 + j;                 // 1KB region = 8 rows
        int row = R * 8 + (lane >> 3);
        int kk = ((lane & 7) ^ (row & 7)) << 3;  // pre-swizzled source k
        load_lds16(gsrc + (size_t)row * 8192 + kk, ldsdst + R * 512);
    }
}

template <int MODE>
__global__ __launch_bounds__(256, 2) void gemm_bf16x3(
    const u16* __restrict__ A2, const u16* __restrict__ B2,
    const float* __restrict__ bias, float* __restrict__ Cf,
    u16* __restrict__ Cb, int M, int N) {
    __shared__ u16 lds[2][2][128 * 64];   // [buf][A/B][row][k] 64 KB total
    const int nTiles = 192;               // K' = 12288 / 64

    int nTn = N >> 7;
    int nwg = (M >> 7) * nTn;
    int bid = blockIdx.x;
    int cpx = nwg >> 3;                   // nwg % 8 == 0 for all our shapes
    int swz = (bid & 7) * cpx + (bid >> 3);
    int tm = swz / nTn, tn = swz % nTn;

    int tid = threadIdx.x, wave = tid >> 6, lane = tid & 63;
    int wm = wave >> 1, wn = wave & 1;

    const u16* Abase = A2 + (size_t)tm * 128 * 8192;
    const u16* Bbase = B2 + (size_t)tn * 128 * 8192;

    f32x4 acc[4][4] = {};

    // prologue: stage tile 0
    {
        int k0 = 0;
        stage_tile(Abase + k0, &lds[0][0][0], wave, lane);
        stage_tile(Bbase + k0, &lds[0][1][0], wave, lane);
    }

#pragma unroll 1
    for (int t = 0; t < nTiles; ++t) {
        int cur = t & 1;
        if (t + 1 < nTiles) {
            int k0 = (t + 1) << 6;
            int kA = (k0 >= 8192) ? k0 - 8192 : k0;
            int kB = (k0 >= 4096) ? k0 - 4096 : k0;
            stage_tile(Abase + kA, &lds[cur ^ 1][0][0], wave, lane);
            stage_tile(Bbase + kB, &lds[cur ^ 1][1][0], wave, lane);
            asm volatile("s_waitcnt vmcnt(8)" ::: "memory");  // drain tile t only
        } else {
            asm volatile("s_waitcnt vmcnt(0)" ::: "memory");
        }
        __builtin_amdgcn_s_barrier();
        asm volatile("" ::: "memory");

        const u16* lA = &lds[cur][0][0];
        const u16* lB = &lds[cur][1][0];
#pragma unroll
        for (int ks = 0; ks < 2; ++ks) {
            int kk = ks * 32 + (lane >> 4) * 8;
            int cq = kk >> 3;
            short8 af[4], bfr[4];
#pragma unroll
            for (int m = 0; m < 4; ++m) {
                int row = wm * 64 + m * 16 + (lane & 15);
                af[m] = *(const short8*)((const char*)lA + row * 128 +
                                         ((cq ^ (row & 7)) << 4));
            }
#pragma unroll
            for (int n = 0; n < 4; ++n) {
                int col = wn * 64 + n * 16 + (lane & 15);
                bfr[n] = *(const short8*)((const char*)lB + col * 128 +
                                          ((cq ^ (col & 7)) << 4));
            }
#pragma unroll
            for (int m = 0; m < 4; ++m)
#pragma unroll
                for (int n = 0; n < 4; ++n)
                    acc[m][n] = __builtin_amdgcn_mfma_f32_16x16x32_bf16(
                        af[m], bfr[n], acc[m][n], 0, 0, 0);
        }
        asm volatile("" ::: "memory");
        __builtin_amdgcn_s_barrier();
    }

    // epilogue: C/D layout col = lane&15, row = (lane>>4)*4 + j
    int rowBase = tm * 128 + wm * 64;
    int colBase = tn * 128 + wn * 64;
#pragma unroll
    for (int n = 0; n < 4; ++n) {
        int col = colBase + n * 16 + (lane & 15);
        float bv = bias[col];
#pragma unroll
        for (int m = 0; m < 4; ++m) {
            int row0 = rowBase + m * 16 + ((lane >> 4) << 2);
#pragma unroll
            for (int j = 0; j < 4; ++j) {
                float v = acc[m][n][j] + bv;
                size_t off = (size_t)(row0 + j) * N + col;
                if (MODE == 0) Cf[off] = v;
                else           Cb[off] = bf16_rn(v > 0.f ? v : 0.f);
            }
        }
    }
}

// ---------------------------------------------------------------------------
// chunk logits: cl[chunk][e] = mean_tokens(H_chunk) @ W2 + b2
// (mean commutes with W2 since relu is already inside H)
// ---------------------------------------------------------------------------
__global__ void chunk_logits_kernel(const u16* __restrict__ H,
                                    const float* __restrict__ W2,
                                    const float* __restrict__ b2,
                                    float* __restrict__ cl) {
    __shared__ float hbar[2048];
    __shared__ float part[256];
    int chunk = blockIdx.x, t = threadIdx.x;
    const u16* h0 = H + (size_t)chunk * 128 * 2048 + t * 8;
    float a[8] = {0, 0, 0, 0, 0, 0, 0, 0};
    for (int i = 0; i < 128; ++i) {
        ushort8v v = *(const ushort8v*)(h0 + (size_t)i * 2048);
#pragma unroll
        for (int j = 0; j < 8; ++j) a[j] += bf16_f(v[j]);
    }
#pragma unroll
    for (int j = 0; j < 8; ++j) hbar[t * 8 + j] = a[j] * (1.f / 128.f);
    __syncthreads();
    int e = t & 7, sl = t >> 3;
    float p = 0.f;
    for (int k = sl * 64; k < sl * 64 + 64; ++k) p += hbar[k] * W2[k * 8 + e];
    part[t] = p;
    __syncthreads();
    if (t < 8) {
        float s = b2[t];
        for (int i = 0; i < 32; ++i) s += part[i * 8 + t];
        cl[chunk * 8 + t] = s;
    }
}

// ---------------------------------------------------------------------------
// chunk-sticky routing with hysteresis (sequential, tiny)
// ---------------------------------------------------------------------------
__global__ void scan_kernel(const float* __restrict__ cl, int* __restrict__ eidx) {
    int b = threadIdx.x;
    if (b >= 2) return;
    const float* c = cl + b * 32 * 8;
    int prev = 0;
    for (int ch = 0; ch < 32; ++ch) {
        const float* v = c + ch * 8;
        int cand = 0; float best = v[0];
#pragma unroll
        for (int e = 1; e < 8; ++e)
            if (v[e] > best) { best = v[e]; cand = e; }   // first-max tie-break
        if (ch == 0) prev = cand;
        else if (v[cand] - v[prev] > 0.7f) prev = cand;
        eidx[b * 32 + ch] = prev;
    }
}

// ---------------------------------------------------------------------------
// LoRA: out[tok] += (x[tok] @ A_e) @ B_e * SCALING, e = expert of tok's chunk
// one wave per token; fp32 exact
// ---------------------------------------------------------------------------
__global__ __launch_bounds__(256) void lora_kernel(
    const float* __restrict__ X, const float* __restrict__ Am,
    const float* __restrict__ Bm, const int* __restrict__ eidx,
    float* __restrict__ out) {
    const float kScaling = 1.0f;  // ALPHA/RANK = 16/16
    int wave = threadIdx.x >> 6, lane = threadIdx.x & 63;
    int tok = blockIdx.x * 4 + wave;
    int b = tok >> 12, s = tok & 4095;
    int e = eidx[b * 32 + (s >> 7)];
    const float* xr = X + (size_t)tok * 4096;
    const float* Ae = Am + (size_t)e * 4096 * 16;
    float ax[16];
#pragma unroll
    for (int r = 0; r < 16; ++r) ax[r] = 0.f;
    for (int k = lane; k < 4096; k += 64) {
        float xv = xr[k];
        const float4* ar = (const float4*)(Ae + (size_t)k * 16);
        float4 a0 = ar[0], a1 = ar[1], a2 = ar[2], a3 = ar[3];
        ax[0]  += xv * a0.x; ax[1]  += xv * a0.y; ax[2]  += xv * a0.z; ax[3]  += xv * a0.w;
        ax[4]  += xv * a1.x; ax[5]  += xv * a1.y; ax[6]  += xv * a1.z; ax[7]  += xv * a1.w;
        ax[8]  += xv * a2.x; ax[9]  += xv * a2.y; ax[10] += xv * a2.z; ax[11] += xv * a2.w;
        ax[12] += xv * a3.x; ax[13] += xv * a3.y; ax[14] += xv * a3.z; ax[15] += xv * a3.w;
    }
#pragma unroll
    for (int r = 0; r < 16; ++r) {
        ax[r] += __shfl_xor(ax[r], 32);
        ax[r] += __shfl_xor(ax[r], 16);
        ax[r] += __shfl_xor(ax[r], 8);
        ax[r] += __shfl_xor(ax[r], 4);
        ax[r] += __shfl_xor(ax[r], 2);
        ax[r] += __shfl_xor(ax[r], 1);
    }
    const float* Be = Bm + (size_t)e * 16 * 4096;
    float* orow = out + (size_t)tok * 4096;
    for (int o = lane; o < 4096; o += 64) {
        float acc = 0.f;
#pragma unroll
        for (int r = 0; r < 16; ++r) acc += ax[r] * Be[(size_t)r * 4096 + o];
        orow[o] += acc * kScaling;
    }
}

// ---------------------------------------------------------------------------
extern "C" void kernel_launch(void* const* d_in, const int* in_sizes, int n_in,
                              void* d_out, int out_size, void* d_ws, size_t ws_size,
                              hipStream_t stream) {
    const float* x  = (const float*)d_in[0];
    const float* Wb = (const float*)d_in[1];
    const float* bb = (const float*)d_in[2];
    const float* W1 = (const float*)d_in[3];
    const float* b1 = (const float*)d_in[4];
    const float* W2 = (const float*)d_in[5];
    const float* b2 = (const float*)d_in[6];
    const float* lA = (const float*)d_in[7];
    const float* lB = (const float*)d_in[8];
    float* out = (float*)d_out;

    char* ws = (char*)d_ws;
    u16*   x2   = (u16*)ws;                     // 8192 x 8192 bf16 (hi|lo) 134.2MB
    u16*   WbT2 = (u16*)(ws + 134217728);       // 4096 x 8192 bf16         67.1MB
    u16*   W1T2 = (u16*)(ws + 201326592);       // 2048 x 8192 bf16         33.6MB
    float* cl   = (float*)(ws + 234881024);     // 64 x 8
    int*   eidx = (int*)(ws + 234883072);       // 64
    u16*   H    = (u16*)d_out;                  // 8192 x 2048 bf16, consumed
                                                // before base GEMM overwrites

    pack_x_kernel<<<32768, 256, 0, stream>>>(x, x2, 4096, 8388608L);
    pack_transpose<<<dim3(128, 128), dim3(32, 8), 0, stream>>>(Wb, WbT2, 4096, 4096);
    pack_transpose<<<dim3(64, 128),  dim3(32, 8), 0, stream>>>(W1, W1T2, 4096, 2048);

    // router: H = relu(x@W1 + b1) in bf16, staged in d_out
    gemm_bf16x3<1><<<1024, 256, 0, stream>>>(x2, W1T2, b1, nullptr, H, 8192, 2048);
    chunk_logits_kernel<<<64, 256, 0, stream>>>(H, W2, b2, cl);
    scan_kernel<<<1, 64, 0, stream>>>(cl, eidx);

    // base: d_out = x@W_base + b_base (overwrites H region, already consumed)
    gemm_bf16x3<0><<<2048, 256, 0, stream>>>(x2, WbT2, bb, out, nullptr, 8192, 4096);

    // out += routed LoRA
    lora_kernel<<<2048, 256, 0, stream>>>(x, lA, lB, eidx, out);
}

// Round 6
// 1615.710 us; speedup vs baseline: 1.2854x; 1.2854x over previous
//
#include <hip/hip_runtime.h>

#define DEVINL __device__ __forceinline__

typedef unsigned short u16;
typedef __attribute__((ext_vector_type(8))) short short8;
typedef __attribute__((ext_vector_type(8))) unsigned short ushort8v;
typedef __attribute__((ext_vector_type(4))) float f32x4;

typedef const __attribute__((address_space(1))) void* gas1_t;
typedef __attribute__((address_space(3))) void* las3_t;

DEVINL u16 bf16_rn(float v) {
    union { float f; unsigned u; } x; x.f = v;
    unsigned r = x.u + 0x7FFFu + ((x.u >> 16) & 1u);
    return (u16)(r >> 16);
}
DEVINL float bf16_f(u16 h) {
    union { unsigned u; float f; } x; x.u = ((unsigned)h) << 16; return x.f;
}

DEVINL void load_lds16(const void* g, void* l) {
    __builtin_amdgcn_global_load_lds((gas1_t)g, (las3_t)l, 16, 0, 0);
}

// ---------------------------------------------------------------------------
// pack x: fp32 [rows][K] -> bf16 [rows][2K] as (hi | lo)
// ---------------------------------------------------------------------------
__global__ void pack_x_kernel(const float* __restrict__ X, u16* __restrict__ out,
                              int K, long total4) {
    long i = (long)blockIdx.x * blockDim.x + threadIdx.x;
    if (i >= total4) return;
    int kq = K >> 2;
    long s = i / kq;
    int c4 = (int)(i % kq);
    float4 v = ((const float4*)X)[i];
    u16 h0 = bf16_rn(v.x), h1 = bf16_rn(v.y), h2 = bf16_rn(v.z), h3 = bf16_rn(v.w);
    u16 l0 = bf16_rn(v.x - bf16_f(h0));
    u16 l1 = bf16_rn(v.y - bf16_f(h1));
    u16 l2 = bf16_rn(v.z - bf16_f(h2));
    u16 l3 = bf16_rn(v.w - bf16_f(h3));
    *(ushort4*)(out + s * (2L * K) + 4L * c4)     = make_ushort4(h0, h1, h2, h3);
    *(ushort4*)(out + s * (2L * K) + K + 4L * c4) = make_ushort4(l0, l1, l2, l3);
}

// ---------------------------------------------------------------------------
// pack + transpose W: fp32 [K][N] -> bf16 [N][2K] as (hi | lo)
// ---------------------------------------------------------------------------
__global__ void pack_transpose(const float* __restrict__ W, u16* __restrict__ out,
                               int K, int N) {
    __shared__ float tile[32][33];
    int nb = blockIdx.x * 32, kb = blockIdx.y * 32;
    int tx = threadIdx.x, ty = threadIdx.y;
#pragma unroll
    for (int i = ty; i < 32; i += 8)
        tile[i][tx] = W[(size_t)(kb + i) * N + nb + tx];
    __syncthreads();
#pragma unroll
    for (int i = ty; i < 32; i += 8) {
        int n = nb + i, k = kb + tx;
        float v = tile[tx][i];
        u16 h = bf16_rn(v);
        u16 l = bf16_rn(v - bf16_f(h));
        out[(size_t)n * (2 * K) + k]     = h;
        out[(size_t)n * (2 * K) + K + k] = l;
    }
}

// ---------------------------------------------------------------------------
// GEMM: C[M][N] = A'[M][K'=12288] * B'[N][K']^T (+bias), bf16x3 compensated.
// Physical A2/B2: [rows][8192] = (hi | lo); logical K' sections:
//   A: [ah | al | ah]  -> kA = k0>=8192 ? k0-8192 : k0
//   B: [bh | bh | bl]  -> kB = k0>=4096 ? k0-4096 : k0
// 256x256 tile, 8 waves (2M x 4N), half-K=32 ring-of-3 LDS pipeline (96 KB):
//   step s: stage hk(s+2) (4 x gload_lds16) | 12 x ds_read_b128 from buf s%3
//           | setprio(1) 32 MFMA setprio(0) | vmcnt(4) lgkmcnt(0) | s_barrier.
//   vmcnt(4) drains hk(s+1) only; 4 loads stay in flight across every barrier.
//   lgkmcnt(0) is free (ds_reads already MFMA-consumed) — hardening against
//   rule-#18 MFMA/waitcnt sinking past the barrier asm.
// LDS swizzle (64B rows): 16B granule g of row r stored at g^((r>>1)&3);
// same involution on pre-swizzled gload source and on ds_read address
// -> each 8-lane b128 service group covers all 32 banks. Conflict-free.
// Accumulation k-order identical to round 1 -> bit-identical numerics.
// ---------------------------------------------------------------------------
template <int MODE>
__global__ __launch_bounds__(512, 2) void gemm256(
    const u16* __restrict__ A2, const u16* __restrict__ B2,
    const float* __restrict__ bias, float* __restrict__ Cf,
    u16* __restrict__ Cb, int M, int N) {
    extern __shared__ u16 lds[];  // [3][2][8192] u16 = 96 KB

    int nTn = N >> 8;
    int nwg = (M >> 8) * nTn;
    int bid = blockIdx.x;
    int cpx = nwg >> 3;                    // nwg % 8 == 0 for our shapes
    int swz = (bid & 7) * cpx + (bid >> 3);
    int tm = swz / nTn, tn = swz % nTn;

    int tid = threadIdx.x, wave = tid >> 6, lane = tid & 63;
    int wm = wave >> 2, wn = wave & 3;     // 2M x 4N waves, each 128x64 of C
    int lrow = lane & 15;

    const u16* Ab = A2 + (size_t)tm * 256 * 8192;
    const u16* Bb = B2 + (size_t)tn * 256 * 8192;

    // staging per-thread source offsets (u16 units); dest is linear lane*16B
    int srow0 = wave * 16 + (lane >> 2);                 // rows 0..127 (j=0)
    int sslot = (lane & 3) ^ ((lane >> 3) & 3);          // inverse-swizzled src
    size_t goff0 = (size_t)srow0 * 8192 + (size_t)sslot * 8;
    size_t goff1 = goff0 + (size_t)128 * 8192;           // rows 128..255 (j=1)
    int sdst = wave * 512;                               // u16; +4096 for j=1

    // per-thread swizzled LDS read offset (u16 units)
    int sgran = (lane >> 4) ^ ((lane >> 1) & 3);
    int aoff = (wm * 128 + lrow) * 32 + sgran * 8;
    int boff = (wn * 64 + lrow) * 32 + sgran * 8;

    f32x4 acc[8][4] = {};

#define STAGEH(BI, K0)                                                        \
    do {                                                                      \
        int k0_ = (K0);                                                       \
        int kA_ = k0_ >= 8192 ? k0_ - 8192 : k0_;                             \
        int kB_ = k0_ >= 4096 ? k0_ - 4096 : k0_;                             \
        u16* bufA_ = lds + (BI) * 16384;                                      \
        u16* bufB_ = bufA_ + 8192;                                            \
        load_lds16(Ab + goff0 + kA_, bufA_ + sdst);                           \
        load_lds16(Ab + goff1 + kA_, bufA_ + 4096 + sdst);                    \
        load_lds16(Bb + goff0 + kB_, bufB_ + sdst);                           \
        load_lds16(Bb + goff1 + kB_, bufB_ + 4096 + sdst);                    \
    } while (0)

#define COMPUTEH(BI)                                                          \
    do {                                                                      \
        const u16* lA_ = lds + (BI) * 16384 + aoff;                           \
        const u16* lB_ = lds + (BI) * 16384 + 8192 + boff;                    \
        short8 a_[8];                                                         \
        short8 b_[4];                                                         \
        _Pragma("unroll") for (int m = 0; m < 8; ++m)                         \
            a_[m] = *(const short8*)(lA_ + m * 512);                          \
        _Pragma("unroll") for (int n = 0; n < 4; ++n)                         \
            b_[n] = *(const short8*)(lB_ + n * 512);                          \
        __builtin_amdgcn_s_setprio(1);                                        \
        _Pragma("unroll") for (int m = 0; m < 8; ++m)                         \
            _Pragma("unroll") for (int n = 0; n < 4; ++n)                     \
                acc[m][n] = __builtin_amdgcn_mfma_f32_16x16x32_bf16(          \
                    a_[m], b_[n], acc[m][n], 0, 0, 0);                        \
        __builtin_amdgcn_s_setprio(0);                                        \
    } while (0)

#define WAITBAR4                                                              \
    do {                                                                      \
        asm volatile("s_waitcnt vmcnt(4) lgkmcnt(0)" ::: "memory");           \
        __builtin_amdgcn_s_barrier();                                         \
        asm volatile("" ::: "memory");                                        \
    } while (0)

    // prologue: stage hk0, hk1; wait hk0 (hk1 stays in flight)
    STAGEH(0, 0);
    STAGEH(1, 32);
    WAITBAR4;

#pragma unroll 1
    for (int t = 0; t < 127; ++t) {
        int s = t * 3;                       // steps s, s+1, s+2 (<= 380)
        STAGEH(2, (s + 2) * 32);
        COMPUTEH(0);
        WAITBAR4;
        STAGEH(0, (s + 3) * 32);
        COMPUTEH(1);
        WAITBAR4;
        STAGEH(1, (s + 4) * 32);
        COMPUTEH(2);
        WAITBAR4;
    }
    // step 381: stage hk383 (into buf2), compute buf0; vmcnt(4) drains hk382
    STAGEH(2, 12256);
    COMPUTEH(0);
    WAITBAR4;
    // step 382: compute buf1; drain hk383 (tail: only place vmcnt hits 0)
    COMPUTEH(1);
    asm volatile("s_waitcnt vmcnt(0) lgkmcnt(0)" ::: "memory");
    __builtin_amdgcn_s_barrier();
    asm volatile("" ::: "memory");
    // step 383
    COMPUTEH(2);

#undef STAGEH
#undef COMPUTEH
#undef WAITBAR4

    // epilogue: C/D layout col = lane&15, row = (lane>>4)*4 + j
    int rowBase = tm * 256 + wm * 128 + ((lane >> 4) << 2);
    int colBase = tn * 256 + wn * 64 + lrow;
#pragma unroll
    for (int n = 0; n < 4; ++n) {
        int col = colBase + n * 16;
        float bv = bias[col];
#pragma unroll
        for (int m = 0; m < 8; ++m) {
            int row0 = rowBase + m * 16;
#pragma unroll
            for (int j = 0; j < 4; ++j) {
                float v = acc[m][n][j] + bv;
                size_t off = (size_t)(row0 + j) * N + col;
                if (MODE == 0) Cf[off] = v;
                else           Cb[off] = bf16_rn(v > 0.f ? v : 0.f);
            }
        }
    }
}

// ---------------------------------------------------------------------------
// chunk logits: cl[chunk][e] = mean_tokens(H_chunk) @ W2 + b2
// ---------------------------------------------------------------------------
__global__ void chunk_logits_kernel(const u16* __restrict__ H,
                                    const float* __restrict__ W2,
                                    const float* __restrict__ b2,
                                    float* __restrict__ cl) {
    __shared__ float hbar[2048];
    __shared__ float part[256];
    int chunk = blockIdx.x, t = threadIdx.x;
    const u16* h0 = H + (size_t)chunk * 128 * 2048 + t * 8;
    float a[8] = {0, 0, 0, 0, 0, 0, 0, 0};
    for (int i = 0; i < 128; ++i) {
        ushort8v v = *(const ushort8v*)(h0 + (size_t)i * 2048);
#pragma unroll
        for (int j = 0; j < 8; ++j) a[j] += bf16_f(v[j]);
    }
#pragma unroll
    for (int j = 0; j < 8; ++j) hbar[t * 8 + j] = a[j] * (1.f / 128.f);
    __syncthreads();
    int e = t & 7, sl = t >> 3;
    float p = 0.f;
    for (int k = sl * 64; k < sl * 64 + 64; ++k) p += hbar[k] * W2[k * 8 + e];
    part[t] = p;
    __syncthreads();
    if (t < 8) {
        float s = b2[t];
        for (int i = 0; i < 32; ++i) s += part[i * 8 + t];
        cl[chunk * 8 + t] = s;
    }
}

// ---------------------------------------------------------------------------
// chunk-sticky routing with hysteresis (sequential, tiny)
// ---------------------------------------------------------------------------
__global__ void scan_kernel(const float* __restrict__ cl, int* __restrict__ eidx) {
    int b = threadIdx.x;
    if (b >= 2) return;
    const float* c = cl + b * 32 * 8;
    int prev = 0;
    for (int ch = 0; ch < 32; ++ch) {
        const float* v = c + ch * 8;
        int cand = 0; float best = v[0];
#pragma unroll
        for (int e = 1; e < 8; ++e)
            if (v[e] > best) { best = v[e]; cand = e; }   // first-max tie-break
        if (ch == 0) prev = cand;
        else if (v[cand] - v[prev] > 0.7f) prev = cand;
        eidx[b * 32 + ch] = prev;
    }
}

// ---------------------------------------------------------------------------
// LoRA: out[tok] += (x[tok] @ A_e) @ B_e, e = expert of tok's chunk (fp32)
// ---------------------------------------------------------------------------
__global__ __launch_bounds__(256) void lora_kernel(
    const float* __restrict__ X, const float* __restrict__ Am,
    const float* __restrict__ Bm, const int* __restrict__ eidx,
    float* __restrict__ out) {
    int wave = threadIdx.x >> 6, lane = threadIdx.x & 63;
    int tok = blockIdx.x * 4 + wave;
    int b = tok >> 12, s = tok & 4095;
    int e = eidx[b * 32 + (s >> 7)];
    const float* xr = X + (size_t)tok * 4096;
    const float* Ae = Am + (size_t)e * 4096 * 16;
    float ax[16];
#pragma unroll
    for (int r = 0; r < 16; ++r) ax[r] = 0.f;
    for (int k = lane; k < 4096; k += 64) {
        float xv = xr[k];
        const float4* ar = (const float4*)(Ae + (size_t)k * 16);
        float4 a0 = ar[0], a1 = ar[1], a2 = ar[2], a3 = ar[3];
        ax[0]  += xv * a0.x; ax[1]  += xv * a0.y; ax[2]  += xv * a0.z; ax[3]  += xv * a0.w;
        ax[4]  += xv * a1.x; ax[5]  += xv * a1.y; ax[6]  += xv * a1.z; ax[7]  += xv * a1.w;
        ax[8]  += xv * a2.x; ax[9]  += xv * a2.y; ax[10] += xv * a2.z; ax[11] += xv * a2.w;
        ax[12] += xv * a3.x; ax[13] += xv * a3.y; ax[14] += xv * a3.z; ax[15] += xv * a3.w;
    }
#pragma unroll
    for (int r = 0; r < 16; ++r) {
        ax[r] += __shfl_xor(ax[r], 32);
        ax[r] += __shfl_xor(ax[r], 16);
        ax[r] += __shfl_xor(ax[r], 8);
        ax[r] += __shfl_xor(ax[r], 4);
        ax[r] += __shfl_xor(ax[r], 2);
        ax[r] += __shfl_xor(ax[r], 1);
    }
    const float* Be = Bm + (size_t)e * 16 * 4096;
    float* orow = out + (size_t)tok * 4096;
    for (int o = lane; o < 4096; o += 64) {
        float acc = 0.f;
#pragma unroll
        for (int r = 0; r < 16; ++r) acc += ax[r] * Be[(size_t)r * 4096 + o];
        orow[o] += acc;     // SCALING = ALPHA/RANK = 1
    }
}

// ---------------------------------------------------------------------------
extern "C" void kernel_launch(void* const* d_in, const int* in_sizes, int n_in,
                              void* d_out, int out_size, void* d_ws, size_t ws_size,
                              hipStream_t stream) {
    const float* x  = (const float*)d_in[0];
    const float* Wb = (const float*)d_in[1];
    const float* bb = (const float*)d_in[2];
    const float* W1 = (const float*)d_in[3];
    const float* b1 = (const float*)d_in[4];
    const float* W2 = (const float*)d_in[5];
    const float* b2 = (const float*)d_in[6];
    const float* lA = (const float*)d_in[7];
    const float* lB = (const float*)d_in[8];
    float* out = (float*)d_out;

    char* ws = (char*)d_ws;
    u16*   x2   = (u16*)ws;                     // 8192 x 8192 bf16 (hi|lo)
    u16*   WbT2 = (u16*)(ws + 134217728);       // 4096 x 8192
    u16*   W1T2 = (u16*)(ws + 201326592);       // 2048 x 8192
    float* cl   = (float*)(ws + 234881024);     // 64 x 8
    int*   eidx = (int*)(ws + 234883072);       // 64
    u16*   H    = (u16*)d_out;                  // 8192 x 2048 bf16, consumed
                                                // before base GEMM overwrites

    hipFuncSetAttribute((const void*)gemm256<1>,
                        hipFuncAttributeMaxDynamicSharedMemorySize, 98304);
    hipFuncSetAttribute((const void*)gemm256<0>,
                        hipFuncAttributeMaxDynamicSharedMemorySize, 98304);

    pack_x_kernel<<<32768, 256, 0, stream>>>(x, x2, 4096, 8388608L);
    pack_transpose<<<dim3(128, 128), dim3(32, 8), 0, stream>>>(Wb, WbT2, 4096, 4096);
    pack_transpose<<<dim3(64, 128),  dim3(32, 8), 0, stream>>>(W1, W1T2, 4096, 2048);

    // router: H = relu(x@W1 + b1) in bf16, staged in d_out
    gemm256<1><<<256, 512, 98304, stream>>>(x2, W1T2, b1, nullptr, H, 8192, 2048);
    chunk_logits_kernel<<<64, 256, 0, stream>>>(H, W2, b2, cl);
    scan_kernel<<<1, 64, 0, stream>>>(cl, eidx);

    // base: d_out = x@W_base + b_base (overwrites H region, already consumed)
    gemm256<0><<<512, 512, 98304, stream>>>(x2, WbT2, bb, out, nullptr, 8192, 4096);

    // out += routed LoRA
    lora_kernel<<<2048, 256, 0, stream>>>(x, lA, lB, eidx, out);
}